// Round 9
// baseline (441.162 us; speedup 1.0000x reference)
//
#include <hip/hip_runtime.h>
#include <math.h>

#define D 128

typedef __attribute__((ext_vector_type(8))) short short8v;
typedef __attribute__((ext_vector_type(4))) float f32x4;

__device__ __forceinline__ unsigned short f2bf(float x) {
    unsigned int u = __float_as_uint(x);
    unsigned int r = (u + 0x7FFFu + ((u >> 16) & 1u)) >> 16;
    return (unsigned short)r;
}
__device__ __forceinline__ float bf2f(unsigned short b) {
    return __uint_as_float(((unsigned int)b) << 16);
}

// ---------------- CSR build ----------------

__global__ void zero_k(int* __restrict__ cnt, int n) {
    int i = blockIdx.x * blockDim.x + threadIdx.x;
    if (i < n) cnt[i] = 0;
}

// rank_k: per-edge arrival rank among same-dst edges (atomic WITH return).
__global__ void rank_k(const int* __restrict__ dst, int E,
                       int* __restrict__ cnt, unsigned short* __restrict__ rank) {
    int e = blockIdx.x * blockDim.x + threadIdx.x;
    if (e < E) rank[e] = (unsigned short)atomicAdd(&cnt[dst[e]], 1);
}

__global__ __launch_bounds__(1024) void scan_a(const int* __restrict__ cnt, int N,
                                               int* __restrict__ part, int* __restrict__ bsum) {
    __shared__ int s[1024];
    int i = blockIdx.x * 1024 + threadIdx.x;
    int v = (i < N) ? cnt[i] : 0;
    s[threadIdx.x] = v;
    __syncthreads();
    for (int off = 1; off < 1024; off <<= 1) {
        int add = (threadIdx.x >= off) ? s[threadIdx.x - off] : 0;
        __syncthreads();
        s[threadIdx.x] += add;
        __syncthreads();
    }
    if (i < N) part[i] = s[threadIdx.x] - v;   // exclusive within chunk
    if (threadIdx.x == 1023) bsum[blockIdx.x] = s[1023];
}

// scan_c with fused block-sum prefix (scan_b eliminated; needs N <= 65536).
__global__ __launch_bounds__(256) void scan_c(const int* __restrict__ cnt, int* __restrict__ part,
                                              const int* __restrict__ bsum,
                                              float* __restrict__ dinv, int N, int E) {
    __shared__ int s_pref;
    int chunk = blockIdx.x >> 2;
    if (threadIdx.x < 64) {
        int v = (threadIdx.x < chunk) ? bsum[threadIdx.x] : 0;
#pragma unroll
        for (int off = 1; off < 64; off <<= 1) v += __shfl_xor(v, off);
        if (threadIdx.x == 0) s_pref = v;
    }
    __syncthreads();
    int i = blockIdx.x * blockDim.x + threadIdx.x;
    if (i < N) {
        part[i] = part[i] + s_pref;
        dinv[i] = rsqrtf((float)(cnt[i] + 1));
    }
    if (i == 0) part[N] = E;
}

// atomic-free fill: position = row_ptr[dst] + rank. ushort col index (N < 65536).
__global__ void fill_k(const int* __restrict__ src, const int* __restrict__ dst,
                       const unsigned short* __restrict__ rank, const int* __restrict__ rp,
                       int E, unsigned short* __restrict__ ssrc) {
    int e = blockIdx.x * blockDim.x + threadIdx.x;
    if (e < E) {
        int p = rp[dst[e]] + (int)rank[e];
        ssrc[p] = (unsigned short)src[e];
    }
}

// ---------------- W split: frag-ordered hi/lo bf16 ----------------

__global__ void wsplit_k(const float* __restrict__ Wp, short* __restrict__ BFh,
                         short* __restrict__ BFl, int total) {
    int idx = blockIdx.x * blockDim.x + threadIdx.x;
    if (idx >= total) return;
    int i    = idx & 7;
    int lane = (idx >> 3) & 63;
    int ct   = (idx >> 9) & 7;
    int ks   = (idx >> 12) & 3;
    int l    = idx >> 14;
    int k = ks * 32 + (lane >> 4) * 8 + i;
    int n = ct * 16 + (lane & 15);
    float w = Wp[(size_t)l * (D * D) + (size_t)k * D + n];
    unsigned short h = f2bf(w);
    float lo = w - bf2f(h);
    BFh[idx] = (short)h;
    BFl[idx] = (short)f2bf(lo);
}

// ---------------- GEMM: HS(bf16, 8 col-slices) = diag(dinv)*(X @ W) ----------
// HS[s][r][c'] holds col c = s*16+c'. Slice = 1.6 MB -> fits one XCD L2.

__global__ __launch_bounds__(256) void gemm_k(const float* __restrict__ X,
                                              const short* __restrict__ BFh,
                                              const short* __restrict__ BFl,
                                              const float* __restrict__ dinv,
                                              unsigned short* __restrict__ HS, int M) {
    int lane = threadIdx.x & 63;
    int wv = threadIdx.x >> 6;
    int rowBase = blockIdx.x * 64 + wv * 16;
    int arow = rowBase + (lane & 15);
    bool aval = arow < M;
    const float* xr = X + (size_t)arow * D + (lane >> 4) * 8;

    short8v ah[4], al[4];
#pragma unroll
    for (int ks = 0; ks < 4; ++ks) {
        float4 p = make_float4(0.f, 0.f, 0.f, 0.f);
        float4 q = make_float4(0.f, 0.f, 0.f, 0.f);
        if (aval) {
            p = *(const float4*)(xr + ks * 32);
            q = *(const float4*)(xr + ks * 32 + 4);
        }
        float v[8] = {p.x, p.y, p.z, p.w, q.x, q.y, q.z, q.w};
#pragma unroll
        for (int i = 0; i < 8; ++i) {
            unsigned short h = f2bf(v[i]);
            ah[ks][i] = (short)h;
            al[ks][i] = (short)f2bf(v[i] - bf2f(h));
        }
    }

    int rb = rowBase + (lane >> 4) * 4;
    float dsc[4];
#pragma unroll
    for (int i = 0; i < 4; ++i) dsc[i] = (rb + i < M) ? dinv[rb + i] : 0.f;

    const short8v* Bh = (const short8v*)BFh;
    const short8v* Bl = (const short8v*)BFl;
#pragma unroll
    for (int ct = 0; ct < 8; ++ct) {
        short8v bh[4], bl[4];
#pragma unroll
        for (int ks = 0; ks < 4; ++ks) {
            bh[ks] = Bh[(ks * 8 + ct) * 64 + lane];
            bl[ks] = Bl[(ks * 8 + ct) * 64 + lane];
        }
        f32x4 acc = {0.f, 0.f, 0.f, 0.f};
#pragma unroll
        for (int ks = 0; ks < 4; ++ks) {
            acc = __builtin_amdgcn_mfma_f32_16x16x32_bf16(ah[ks], bh[ks], acc, 0, 0, 0);
            acc = __builtin_amdgcn_mfma_f32_16x16x32_bf16(al[ks], bh[ks], acc, 0, 0, 0);
            acc = __builtin_amdgcn_mfma_f32_16x16x32_bf16(ah[ks], bl[ks], acc, 0, 0, 0);
        }
#pragma unroll
        for (int i = 0; i < 4; ++i) {
            int r = rb + i;
            if (r < M) HS[((size_t)ct * M + r) * 16 + (lane & 15)] = f2bf(dsc[i] * acc[i]);
        }
    }
}

// ---------------- sparse aggregation: XCD column-sliced --------------------
// out[n][s*16..] = b + dinv[n]*( hs[n] + sum_e hs[ssrc[e]] ), slice s = bid%8.
// Under round-robin blockIdx->XCD mapping each XCD's L2 only holds slice s
// (1.6 MB) + ssrc (1.6 MB) -> all gathers are L2 hits. Wave per node-slice:
// 16 edges/round (g=lane>>2), uint2 (4 cols)/lane, butterfly over g bits.

__device__ __forceinline__ float gelu_f(float x) {
    return 0.5f * x * (1.0f + erff(x * 0.70710678118654752f));
}

__global__ __launch_bounds__(256) void agg_k(const unsigned short* __restrict__ HS,
                                             const int* __restrict__ rp,
                                             const unsigned short* __restrict__ ssrc,
                                             const float* __restrict__ dinv,
                                             const float* __restrict__ bias,
                                             float* __restrict__ out, int N, int doGelu) {
    int slice = blockIdx.x & 7;
    int node  = (blockIdx.x >> 3) * 4 + (threadIdx.x >> 6);
    int lane  = threadIdx.x & 63;
    if (node >= N) return;
    int g = lane >> 2, sub = lane & 3;
    const uint2* __restrict__ hs = (const uint2*)(HS + (size_t)slice * N * 16);  // row = 4 uint2

    float a0 = 0.f, a1 = 0.f, a2 = 0.f, a3 = 0.f;
    int e0 = rp[node];
    int e1 = rp[node + 1];
    for (int base = e0; base < e1; base += 64) {
        int idxv = 0;                                         // masked -> row 0 (L2-hot)
        if (base + lane < e1) idxv = (int)ssrc[base + lane];  // coalesced, L2-resident
        int cnt = e1 - base; if (cnt > 64) cnt = 64;
        for (int c = 0; c < cnt; c += 16) {                   // 16 edges per round
            int row = __shfl(idxv, c + g);
            uint2 v = hs[(size_t)row * 4 + sub];
            bool ok = (base + c + g) < e1;
            unsigned int w;
            w = ok ? v.x : 0u;
            a0 += __uint_as_float(w << 16); a1 += __uint_as_float(w & 0xFFFF0000u);
            w = ok ? v.y : 0u;
            a2 += __uint_as_float(w << 16); a3 += __uint_as_float(w & 0xFFFF0000u);
        }
    }
    // combine the 16 edge-groups (lane bits 2..5)
#pragma unroll
    for (int m = 4; m < 64; m <<= 1) {
        a0 += __shfl_xor(a0, m);
        a1 += __shfl_xor(a1, m);
        a2 += __shfl_xor(a2, m);
        a3 += __shfl_xor(a3, m);
    }
    if (g == 0) {
        uint2 sv = hs[(size_t)node * 4 + sub];                // self term
        a0 += __uint_as_float(sv.x << 16); a1 += __uint_as_float(sv.x & 0xFFFF0000u);
        a2 += __uint_as_float(sv.y << 16); a3 += __uint_as_float(sv.y & 0xFFFF0000u);
        float dn = dinv[node];
        float4 bv = ((const float4*)bias)[slice * 4 + sub];
        float r0 = dn * a0 + bv.x;
        float r1 = dn * a1 + bv.y;
        float r2 = dn * a2 + bv.z;
        float r3 = dn * a3 + bv.w;
        if (doGelu) { r0 = gelu_f(r0); r1 = gelu_f(r1); r2 = gelu_f(r2); r3 = gelu_f(r3); }
        ((float4*)out)[(size_t)node * 32 + slice * 4 + sub] = make_float4(r0, r1, r2, r3);
    }
}

// ---------------- launch ----------------

extern "C" void kernel_launch(void* const* d_in, const int* in_sizes, int n_in,
                              void* d_out, int out_size, void* d_ws, size_t ws_size,
                              hipStream_t stream) {
    const float* X  = (const float*)d_in[0];
    const int*   EI = (const int*)d_in[1];
    const float* Wp = (const float*)d_in[2];
    const float* bp = (const float*)d_in[3];
    float* OUT = (float*)d_out;

    int N = in_sizes[0] / D;
    int E = in_sizes[1] / 2;
    int L = in_sizes[3] / D;
    const int* src = EI;
    const int* dst = EI + E;

    char* w = (char*)d_ws;
    auto alloc = [&](size_t bytes) {
        char* p = w;
        w += (bytes + 255) & ~(size_t)255;
        return p;
    };
    unsigned short* HB = (unsigned short*)alloc((size_t)N * D * sizeof(unsigned short)); // 12.8 MB, sliced
    float* XB   = (float*)alloc((size_t)N * D * sizeof(float));   // 25.6 MB
    float* DINV = (float*)alloc((size_t)N * sizeof(float));
    int*   RP   = (int*)alloc((size_t)(N + 1) * sizeof(int));
    int*   CNT  = (int*)alloc((size_t)N * sizeof(int));
    int*   BSUM = (int*)alloc(4096 * sizeof(int));
    unsigned short* RANK = (unsigned short*)alloc((size_t)E * sizeof(unsigned short));
    unsigned short* SSRC = (unsigned short*)alloc(((size_t)E + 64) * sizeof(unsigned short));
    short* BFH  = (short*)alloc((size_t)L * D * D * sizeof(short));
    short* BFL  = (short*)alloc((size_t)L * D * D * sizeof(short));
    (void)ws_size; (void)n_in; (void)out_size;

    zero_k<<<(N + 255) / 256, 256, 0, stream>>>(CNT, N);

    int eb = (E + 255) / 256;
    rank_k<<<eb, 256, 0, stream>>>(dst, E, CNT, RANK);
    int nb = (N + 1023) / 1024;
    scan_a<<<nb, 1024, 0, stream>>>(CNT, N, RP, BSUM);
    scan_c<<<(N + 255) / 256, 256, 0, stream>>>(CNT, RP, BSUM, DINV, N, E);
    fill_k<<<eb, 256, 0, stream>>>(src, dst, RANK, RP, E, SSRC);

    int wtot = L * D * D;
    wsplit_k<<<(wtot + 255) / 256, 256, 0, stream>>>(Wp, BFH, BFL, wtot);

    int gb = (N + 63) / 64;
    int ab = ((N + 3) / 4) * 8;   // node-blocks x 8 column slices
    for (int l = 0; l < L; ++l) {
        const float* xin = (l == 0) ? X : XB;
        gemm_k<<<gb, 256, 0, stream>>>(xin, BFH + (size_t)l * D * D, BFL + (size_t)l * D * D,
                                       DINV, HB, N);
        float* o = (l == L - 1) ? OUT : XB;
        agg_k<<<ab, 256, 0, stream>>>(HB, RP, SSRC, DINV, bp + (size_t)l * D, o, N,
                                      (l == L - 1) ? 1 : 0);
    }
}

// Round 10
// 218.782 us; speedup vs baseline: 2.0164x; 2.0164x over previous
//
#include <hip/hip_runtime.h>
#include <math.h>

#define D 128

typedef __attribute__((ext_vector_type(8))) short short8v;
typedef __attribute__((ext_vector_type(4))) float f32x4;

__device__ __forceinline__ unsigned short f2bf(float x) {
    unsigned int u = __float_as_uint(x);
    unsigned int r = (u + 0x7FFFu + ((u >> 16) & 1u)) >> 16;
    return (unsigned short)r;
}
__device__ __forceinline__ float bf2f(unsigned short b) {
    return __uint_as_float(((unsigned int)b) << 16);
}

// ---------------- CSR build ----------------

__global__ void zero_k(int* __restrict__ cnt, int n) {
    int i = blockIdx.x * blockDim.x + threadIdx.x;
    if (i < n) cnt[i] = 0;
}

__global__ void rank_k(const int* __restrict__ dst, int E,
                       int* __restrict__ cnt, unsigned short* __restrict__ rank) {
    int e = blockIdx.x * blockDim.x + threadIdx.x;
    if (e < E) rank[e] = (unsigned short)atomicAdd(&cnt[dst[e]], 1);
}

__global__ __launch_bounds__(1024) void scan_a(const int* __restrict__ cnt, int N,
                                               int* __restrict__ part, int* __restrict__ bsum) {
    __shared__ int s[1024];
    int i = blockIdx.x * 1024 + threadIdx.x;
    int v = (i < N) ? cnt[i] : 0;
    s[threadIdx.x] = v;
    __syncthreads();
    for (int off = 1; off < 1024; off <<= 1) {
        int add = (threadIdx.x >= off) ? s[threadIdx.x - off] : 0;
        __syncthreads();
        s[threadIdx.x] += add;
        __syncthreads();
    }
    if (i < N) part[i] = s[threadIdx.x] - v;
    if (threadIdx.x == 1023) bsum[blockIdx.x] = s[1023];
}

// scan_c with fused block-sum prefix (needs N <= 65536).
__global__ __launch_bounds__(256) void scan_c(const int* __restrict__ cnt, int* __restrict__ part,
                                              const int* __restrict__ bsum,
                                              float* __restrict__ dinv, int N, int E) {
    __shared__ int s_pref;
    int chunk = blockIdx.x >> 2;
    if (threadIdx.x < 64) {
        int v = (threadIdx.x < chunk) ? bsum[threadIdx.x] : 0;
#pragma unroll
        for (int off = 1; off < 64; off <<= 1) v += __shfl_xor(v, off);
        if (threadIdx.x == 0) s_pref = v;
    }
    __syncthreads();
    int i = blockIdx.x * blockDim.x + threadIdx.x;
    if (i < N) {
        part[i] = part[i] + s_pref;
        dinv[i] = rsqrtf((float)(cnt[i] + 1));
    }
    if (i == 0) part[N] = E;
}

__global__ void fill_k(const int* __restrict__ src, const int* __restrict__ dst,
                       const unsigned short* __restrict__ rank, const int* __restrict__ rp,
                       int E, unsigned short* __restrict__ ssrc) {
    int e = blockIdx.x * blockDim.x + threadIdx.x;
    if (e < E) {
        int p = rp[dst[e]] + (int)rank[e];
        ssrc[p] = (unsigned short)src[e];
    }
}

// ---------------- W split: frag-ordered hi/lo bf16 ----------------

__global__ void wsplit_k(const float* __restrict__ Wp, short* __restrict__ BFh,
                         short* __restrict__ BFl, int total) {
    int idx = blockIdx.x * blockDim.x + threadIdx.x;
    if (idx >= total) return;
    int i    = idx & 7;
    int lane = (idx >> 3) & 63;
    int ct   = (idx >> 9) & 7;
    int ks   = (idx >> 12) & 3;
    int l    = idx >> 14;
    int k = ks * 32 + (lane >> 4) * 8 + i;
    int n = ct * 16 + (lane & 15);
    float w = Wp[(size_t)l * (D * D) + (size_t)k * D + n];
    unsigned short h = f2bf(w);
    float lo = w - bf2f(h);
    BFh[idx] = (short)h;
    BFl[idx] = (short)f2bf(lo);
}

// ---------------- GEMM: Hb(bf16) = diag(dinv) * (X(f32) @ W), split-bf16 MFMA ----

__global__ __launch_bounds__(256) void gemm_k(const float* __restrict__ X,
                                              const short* __restrict__ BFh,
                                              const short* __restrict__ BFl,
                                              const float* __restrict__ dinv,
                                              unsigned short* __restrict__ Hb, int M) {
    int lane = threadIdx.x & 63;
    int wv = threadIdx.x >> 6;
    int rowBase = blockIdx.x * 64 + wv * 16;
    int arow = rowBase + (lane & 15);
    bool aval = arow < M;
    const float* xr = X + (size_t)arow * D + (lane >> 4) * 8;

    short8v ah[4], al[4];
#pragma unroll
    for (int ks = 0; ks < 4; ++ks) {
        float4 p = make_float4(0.f, 0.f, 0.f, 0.f);
        float4 q = make_float4(0.f, 0.f, 0.f, 0.f);
        if (aval) {
            p = *(const float4*)(xr + ks * 32);
            q = *(const float4*)(xr + ks * 32 + 4);
        }
        float v[8] = {p.x, p.y, p.z, p.w, q.x, q.y, q.z, q.w};
#pragma unroll
        for (int i = 0; i < 8; ++i) {
            unsigned short h = f2bf(v[i]);
            ah[ks][i] = (short)h;
            al[ks][i] = (short)f2bf(v[i] - bf2f(h));
        }
    }

    int rb = rowBase + (lane >> 4) * 4;
    float dsc[4];
#pragma unroll
    for (int i = 0; i < 4; ++i) dsc[i] = (rb + i < M) ? dinv[rb + i] : 0.f;

    const short8v* Bh = (const short8v*)BFh;
    const short8v* Bl = (const short8v*)BFl;
#pragma unroll
    for (int ct = 0; ct < 8; ++ct) {
        short8v bh[4], bl[4];
#pragma unroll
        for (int ks = 0; ks < 4; ++ks) {
            bh[ks] = Bh[(ks * 8 + ct) * 64 + lane];
            bl[ks] = Bl[(ks * 8 + ct) * 64 + lane];
        }
        f32x4 acc = {0.f, 0.f, 0.f, 0.f};
#pragma unroll
        for (int ks = 0; ks < 4; ++ks) {
            acc = __builtin_amdgcn_mfma_f32_16x16x32_bf16(ah[ks], bh[ks], acc, 0, 0, 0);
            acc = __builtin_amdgcn_mfma_f32_16x16x32_bf16(al[ks], bh[ks], acc, 0, 0, 0);
            acc = __builtin_amdgcn_mfma_f32_16x16x32_bf16(ah[ks], bl[ks], acc, 0, 0, 0);
        }
        int c = ct * 16 + (lane & 15);
#pragma unroll
        for (int i = 0; i < 4; ++i) {
            int r = rb + i;
            if (r < M) Hb[(size_t)r * D + c] = f2bf(dsc[i] * acc[i]);
        }
    }
}

// ---------------- FUSED: agg(l) -> bf16-split A-tile in LDS -> gemm(l+1) ------
// Phase 1 (per wave, 16 nodes seq): out_row = bias + dinv[n]*(h'[n]+sum h'[src]),
// split hi/lo bf16, packed to LDS (row-padded to kill bank conflicts).
// Phase 2: standard split-bf16 MFMA vs W_{l+1}; writes diag(dinv)*(out @ W) bf16.
// No __syncthreads needed: each wave consumes only its own LDS region.

__global__ __launch_bounds__(256) void aggmm_k(const unsigned short* __restrict__ Hin,
                                               const int* __restrict__ rp,
                                               const unsigned short* __restrict__ ssrc,
                                               const float* __restrict__ dinv,
                                               const float* __restrict__ bias,
                                               const short* __restrict__ BFh,
                                               const short* __restrict__ BFl,
                                               unsigned short* __restrict__ Hout, int N) {
    __shared__ unsigned int AH[4][16][68];   // hi bf16 pair per uint; 68-pad (272B row)
    __shared__ unsigned int AL[4][16][68];   // lo
    int lane = threadIdx.x & 63;
    int wv = threadIdx.x >> 6;
    int rowBase = blockIdx.x * 64 + wv * 16;
    const unsigned int* __restrict__ hb = (const unsigned int*)Hin;
    float2 bv = ((const float2*)bias)[lane];

    // ---- phase 1: aggregate 16 nodes ----
    for (int rr = 0; rr < 16; ++rr) {
        int node = rowBase + rr;
        float r0 = 0.f, r1 = 0.f;
        if (node < N) {
            unsigned int sv = hb[(size_t)node * 64 + lane];
            float ax = __uint_as_float(sv << 16);
            float ay = __uint_as_float(sv & 0xFFFF0000u);
            float bx = 0.f, by = 0.f;
            int e0 = rp[node];
            int e1 = rp[node + 1];
            for (int base = e0; base < e1; base += 64) {
                int idxv = 0;
                if (base + lane < e1) idxv = (int)ssrc[base + lane];
                int cnt = e1 - base; if (cnt > 64) cnt = 64;
                for (int c = 0; c < cnt; c += 16) {
                    int s[16];
                    unsigned int v[16];
#pragma unroll
                    for (int j = 0; j < 16; ++j) s[j] = __shfl(idxv, c + j);
#pragma unroll
                    for (int j = 0; j < 16; ++j) v[j] = hb[(size_t)s[j] * 64 + lane];
#pragma unroll
                    for (int j = 0; j < 16; ++j) {
                        unsigned int m = (c + j < cnt) ? v[j] : 0u;
                        float fx = __uint_as_float(m << 16);
                        float fy = __uint_as_float(m & 0xFFFF0000u);
                        if (j & 1) { bx += fx; by += fy; }
                        else       { ax += fx; ay += fy; }
                    }
                }
            }
            ax += bx; ay += by;
            float dn = dinv[node];
            r0 = dn * ax + bv.x;
            r1 = dn * ay + bv.y;
        }
        unsigned short h0 = f2bf(r0);
        unsigned short h1 = f2bf(r1);
        unsigned short l0 = f2bf(r0 - bf2f(h0));
        unsigned short l1 = f2bf(r1 - bf2f(h1));
        AH[wv][rr][lane] = (unsigned int)h0 | ((unsigned int)h1 << 16);
        AL[wv][rr][lane] = (unsigned int)l0 | ((unsigned int)l1 << 16);
    }

    // ---- phase 2: MFMA vs W_{l+1} (A from LDS) ----
    short8v ah[4], al[4];
    int arow = lane & 15;
    int kq = (lane >> 4) * 4;     // uint offset of this lane's 8-bf16 k-block
#pragma unroll
    for (int ks = 0; ks < 4; ++ks) {
        ah[ks] = *(const short8v*)&AH[wv][arow][ks * 16 + kq];
        al[ks] = *(const short8v*)&AL[wv][arow][ks * 16 + kq];
    }

    int rb = rowBase + (lane >> 4) * 4;
    float dsc[4];
#pragma unroll
    for (int i = 0; i < 4; ++i) dsc[i] = (rb + i < N) ? dinv[rb + i] : 0.f;

    const short8v* Bh = (const short8v*)BFh;
    const short8v* Bl = (const short8v*)BFl;
#pragma unroll
    for (int ct = 0; ct < 8; ++ct) {
        short8v bh[4], bl[4];
#pragma unroll
        for (int ks = 0; ks < 4; ++ks) {
            bh[ks] = Bh[(ks * 8 + ct) * 64 + lane];
            bl[ks] = Bl[(ks * 8 + ct) * 64 + lane];
        }
        f32x4 acc = {0.f, 0.f, 0.f, 0.f};
#pragma unroll
        for (int ks = 0; ks < 4; ++ks) {
            acc = __builtin_amdgcn_mfma_f32_16x16x32_bf16(ah[ks], bh[ks], acc, 0, 0, 0);
            acc = __builtin_amdgcn_mfma_f32_16x16x32_bf16(al[ks], bh[ks], acc, 0, 0, 0);
            acc = __builtin_amdgcn_mfma_f32_16x16x32_bf16(ah[ks], bl[ks], acc, 0, 0, 0);
        }
        int c = ct * 16 + (lane & 15);
#pragma unroll
        for (int i = 0; i < 4; ++i) {
            int r = rb + i;
            if (r < N) Hout[(size_t)r * D + c] = f2bf(dsc[i] * acc[i]);
        }
    }
}

// ---------------- final aggregation (round-8 v4, bf16 gathers, 4 rows/instr) --

__device__ __forceinline__ float gelu_f(float x) {
    return 0.5f * x * (1.0f + erff(x * 0.70710678118654752f));
}

__global__ __launch_bounds__(256) void agg_k(const unsigned short* __restrict__ Hb,
                                             const int* __restrict__ rp,
                                             const unsigned short* __restrict__ ssrc,
                                             const float* __restrict__ dinv,
                                             const float* __restrict__ bias,
                                             float* __restrict__ out, int N) {
    int node = blockIdx.x * 4 + (threadIdx.x >> 6);
    int lane = threadIdx.x & 63;
    if (node >= N) return;
    const uint4* __restrict__ hb4 = (const uint4*)Hb;
    int grp = lane >> 4;
    int sub = lane & 15;

    float acc[8];
#pragma unroll
    for (int i = 0; i < 8; ++i) acc[i] = 0.f;

    int e0 = rp[node];
    int e1 = rp[node + 1];
    for (int base = e0; base < e1; base += 64) {
        int idxv = 0;
        if (base + lane < e1) idxv = (int)ssrc[base + lane];
        int cnt = e1 - base; if (cnt > 64) cnt = 64;
        for (int c = 0; c < cnt; c += 16) {
            uint4 v[4];
#pragma unroll
            for (int j = 0; j < 4; ++j) {
                int row = __shfl(idxv, c + 4 * j + grp);
                v[j] = hb4[(size_t)row * 16 + sub];
            }
#pragma unroll
            for (int j = 0; j < 4; ++j) {
                bool ok = (base + c + 4 * j + grp) < e1;
                unsigned int w;
                w = ok ? v[j].x : 0u;
                acc[0] += __uint_as_float(w << 16); acc[1] += __uint_as_float(w & 0xFFFF0000u);
                w = ok ? v[j].y : 0u;
                acc[2] += __uint_as_float(w << 16); acc[3] += __uint_as_float(w & 0xFFFF0000u);
                w = ok ? v[j].z : 0u;
                acc[4] += __uint_as_float(w << 16); acc[5] += __uint_as_float(w & 0xFFFF0000u);
                w = ok ? v[j].w : 0u;
                acc[6] += __uint_as_float(w << 16); acc[7] += __uint_as_float(w & 0xFFFF0000u);
            }
        }
    }
#pragma unroll
    for (int i = 0; i < 8; ++i) {
        acc[i] += __shfl_xor(acc[i], 16);
        acc[i] += __shfl_xor(acc[i], 32);
    }
    if (lane < 16) {
        uint4 sv = hb4[(size_t)node * 16 + lane];
        acc[0] += __uint_as_float(sv.x << 16); acc[1] += __uint_as_float(sv.x & 0xFFFF0000u);
        acc[2] += __uint_as_float(sv.y << 16); acc[3] += __uint_as_float(sv.y & 0xFFFF0000u);
        acc[4] += __uint_as_float(sv.z << 16); acc[5] += __uint_as_float(sv.z & 0xFFFF0000u);
        acc[6] += __uint_as_float(sv.w << 16); acc[7] += __uint_as_float(sv.w & 0xFFFF0000u);
        float dn = dinv[node];
        float4 b0 = ((const float4*)bias)[lane * 2];
        float4 b1 = ((const float4*)bias)[lane * 2 + 1];
        float r[8];
        r[0] = dn * acc[0] + b0.x; r[1] = dn * acc[1] + b0.y;
        r[2] = dn * acc[2] + b0.z; r[3] = dn * acc[3] + b0.w;
        r[4] = dn * acc[4] + b1.x; r[5] = dn * acc[5] + b1.y;
        r[6] = dn * acc[6] + b1.z; r[7] = dn * acc[7] + b1.w;
#pragma unroll
        for (int i = 0; i < 8; ++i) r[i] = gelu_f(r[i]);
        float4 o0 = make_float4(r[0], r[1], r[2], r[3]);
        float4 o1 = make_float4(r[4], r[5], r[6], r[7]);
        ((float4*)out)[(size_t)node * 32 + lane * 2]     = o0;
        ((float4*)out)[(size_t)node * 32 + lane * 2 + 1] = o1;
    }
}

// ---------------- launch ----------------

extern "C" void kernel_launch(void* const* d_in, const int* in_sizes, int n_in,
                              void* d_out, int out_size, void* d_ws, size_t ws_size,
                              hipStream_t stream) {
    const float* X  = (const float*)d_in[0];
    const int*   EI = (const int*)d_in[1];
    const float* Wp = (const float*)d_in[2];
    const float* bp = (const float*)d_in[3];
    float* OUT = (float*)d_out;

    int N = in_sizes[0] / D;
    int E = in_sizes[1] / 2;
    int L = in_sizes[3] / D;   // 3
    const int* src = EI;
    const int* dst = EI + E;

    char* w = (char*)d_ws;
    auto alloc = [&](size_t bytes) {
        char* p = w;
        w += (bytes + 255) & ~(size_t)255;
        return p;
    };
    unsigned short* HA = (unsigned short*)alloc((size_t)N * D * sizeof(unsigned short)); // 12.8 MB
    unsigned short* HBuf = (unsigned short*)alloc((size_t)N * D * sizeof(unsigned short)); // 12.8 MB
    float* DINV = (float*)alloc((size_t)N * sizeof(float));
    int*   RP   = (int*)alloc((size_t)(N + 1) * sizeof(int));
    int*   CNT  = (int*)alloc((size_t)N * sizeof(int));
    int*   BSUM = (int*)alloc(4096 * sizeof(int));
    unsigned short* RANK = (unsigned short*)alloc((size_t)E * sizeof(unsigned short));
    unsigned short* SSRC = (unsigned short*)alloc(((size_t)E + 64) * sizeof(unsigned short));
    short* BFH  = (short*)alloc((size_t)L * D * D * sizeof(short));
    short* BFL  = (short*)alloc((size_t)L * D * D * sizeof(short));
    (void)ws_size; (void)n_in; (void)out_size;

    zero_k<<<(N + 255) / 256, 256, 0, stream>>>(CNT, N);

    int eb = (E + 255) / 256;
    rank_k<<<eb, 256, 0, stream>>>(dst, E, CNT, RANK);
    int nb = (N + 1023) / 1024;
    scan_a<<<nb, 1024, 0, stream>>>(CNT, N, RP, BSUM);
    scan_c<<<(N + 255) / 256, 256, 0, stream>>>(CNT, RP, BSUM, DINV, N, E);
    fill_k<<<eb, 256, 0, stream>>>(src, dst, RANK, RP, E, SSRC);

    int wtot = L * D * D;
    wsplit_k<<<(wtot + 255) / 256, 256, 0, stream>>>(Wp, BFH, BFL, wtot);

    int gb = (N + 63) / 64;
    // layer 0 linear: H0' = diag(dinv) * (X @ W0)
    gemm_k<<<gb, 256, 0, stream>>>(X, BFH, BFL, DINV, HA, N);
    // fused: agg(l) + linear(l+1), for l = 0..L-2
    aggmm_k<<<gb, 256, 0, stream>>>(HA, RP, SSRC, DINV, bp,
                                    BFH + (size_t)1 * D * D, BFL + (size_t)1 * D * D,
                                    HBuf, N);
    aggmm_k<<<gb, 256, 0, stream>>>(HBuf, RP, SSRC, DINV, bp + D,
                                    BFH + (size_t)2 * D * D, BFL + (size_t)2 * D * D,
                                    HA, N);
    // final aggregation + bias + GELU
    int ab = (N + 3) / 4;
    agg_k<<<ab, 256, 0, stream>>>(HA, RP, SSRC, DINV, bp + 2 * D, OUT, N);
}